// Round 2
// baseline (1737.873 us; speedup 1.0000x reference)
//
#include <hip/hip_runtime.h>

#define NS   16384
#define NIN  16384
#define CIN  128
#define COUT 128
#define KNB  9
#define MCH  66              // 64 MLP channels + 1 (b3 ones) + 1 zero pad
#define QDIM (CIN*MCH)       // 8448 = 264*32
#define KIT  (QDIM/32)       // 264
#define W0C  30.0f

typedef __bf16 bf16;
typedef bf16  bf16x8  __attribute__((ext_vector_type(8)));
typedef float floatx4 __attribute__((ext_vector_type(4)));
typedef unsigned int u32;

__device__ inline unsigned short f2bf(float f){
  u32 u = __float_as_uint(f);
  u += 0x7fffu + ((u >> 16) & 1u);   // round-to-nearest-even
  return (unsigned short)(u >> 16);
}
__device__ inline u32 pack2bf(float lo, float hi){
  return (u32)f2bf(lo) | ((u32)f2bf(hi) << 16);
}
__device__ inline float bf2f(unsigned short s){
  return __uint_as_float((u32)s << 16);
}

__device__ inline void gload16(const void* g, void* s){
  __builtin_amdgcn_global_load_lds(
      (const __attribute__((address_space(1))) u32*)g,
      (__attribute__((address_space(3))) u32*)s, 16, 0, 0);
}

// ---------------- K0: Vt[i][q] bf16, q = j*66+m ----------------
__global__ void k0_vt(const float* __restrict__ W3, const float* __restrict__ b3,
                      unsigned short* __restrict__ Vt){
  int idx = blockIdx.x*256 + threadIdx.x;
  if (idx >= COUT*QDIM) return;
  int i = idx / QDIM;
  int q = idx - i*QDIM;
  int j = q / MCH;
  int m = q - j*MCH;
  float v = 0.f;
  if (m < 64)       v = W3[m*16384 + i*128 + j];
  else if (m == 64) v = b3[i*128 + j];
  Vt[idx] = f2bf(v);
}

// ---------------- K1: SIREN MLP (fp32), one wave per point ----------------
__global__ __launch_bounds__(256) void k1_mlp(const float* __restrict__ coords,
      const float* __restrict__ W1, const float* __restrict__ b1,
      const float* __restrict__ W2, const float* __restrict__ b2,
      float* __restrict__ h){
  int lane = threadIdx.x & 63;
  int pt = blockIdx.x*4 + (threadIdx.x >> 6);
  float c0 = coords[2*pt], c1 = coords[2*pt+1];
  float z  = fmaf(c0, W1[lane], fmaf(c1, W1[64+lane], b1[lane]));
  float h1 = sinf(W0C * z);
  float acc = b2[lane];
  #pragma unroll
  for (int mp = 0; mp < 64; ++mp)
    acc = fmaf(__shfl(h1, mp, 64), W2[mp*64 + lane], acc);
  float h2 = sinf(acc);
  size_t base = (size_t)pt * MCH;
  h[base + lane] = h2;
  if (lane == 0){ h[base+64] = 1.f; h[base+65] = 0.f; }
}

// ---------------- K1b: transpose x[b][j][p] -> xT[b][p][j] (bf16) ----------------
__global__ void k_tr(const float* __restrict__ x, unsigned short* __restrict__ xT){
  __shared__ __align__(16) float t[32][33];
  int b  = blockIdx.z;
  int j0 = blockIdx.y*32;
  int p0 = blockIdx.x*32;
  int tx = threadIdx.x, ty = threadIdx.y;
  const float*    xb  = x  + (size_t)b*CIN*NIN;
  unsigned short* xTb = xT + (size_t)b*NIN*CIN;
  #pragma unroll
  for (int n = 0; n < 4; ++n)
    t[ty+8*n][tx] = xb[(size_t)(j0+ty+8*n)*NIN + p0+tx];
  __syncthreads();
  #pragma unroll
  for (int n = 0; n < 4; ++n)
    xTb[(size_t)(p0+ty+8*n)*CIN + j0+tx] = f2bf(t[tx][ty+8*n]);
}

// ---------------- K2: u[r][q] = sum_k xT[b][n[k,l]][j]*h[k*NS+l][m] ----------------
__global__ __launch_bounds__(128) void k2_uform(const unsigned short* __restrict__ xT,
      const float* __restrict__ h, const int* __restrict__ nb,
      unsigned short* __restrict__ U, int r0){
  __shared__ __align__(16) float hl[KNB][68];
  __shared__ int pk[KNB];
  int tid = threadIdx.x;
  int r = r0 + blockIdx.x;
  int b = r >> 14;
  int l = r & (NS-1);
  for (int idx = tid; idx < KNB*MCH; idx += 128){
    int k = idx / MCH;
    int m = idx - k*MCH;
    hl[k][m] = h[(size_t)(k*NS + l)*MCH + m];
  }
  if (tid < KNB) pk[tid] = nb[tid*NS + l];
  __syncthreads();
  const unsigned short* xb = xT + ((size_t)b << 21);   // b*NIN*CIN
  float acc[65];
  #pragma unroll
  for (int t = 0; t < 65; ++t) acc[t] = 0.f;
  #pragma unroll
  for (int k = 0; k < KNB; ++k){
    float xv = bf2f(xb[((size_t)pk[k] << 7) + tid]);
    #pragma unroll
    for (int t = 0; t < 16; ++t){
      float4 hv = *(const float4*)&hl[k][4*t];
      acc[4*t+0] = fmaf(xv, hv.x, acc[4*t+0]);
      acc[4*t+1] = fmaf(xv, hv.y, acc[4*t+1]);
      acc[4*t+2] = fmaf(xv, hv.z, acc[4*t+2]);
      acc[4*t+3] = fmaf(xv, hv.w, acc[4*t+3]);
    }
    acc[64] += xv;   // h channel 64 == 1  (b3 path)
  }
  u32* dst = (u32*)((char*)U + ((size_t)blockIdx.x*QDIM + (size_t)tid*MCH)*2);
  #pragma unroll
  for (int t = 0; t < 32; ++t) dst[t] = pack2bf(acc[2*t], acc[2*t+1]);
  dst[32] = pack2bf(acc[64], 0.f);             // channel 65 == 0
}

// ---------------- K3: out[(b,l)][i] = U @ Vt^T, m97-style MFMA GEMM ----------------
__global__ __launch_bounds__(256) void k3_gemm(const unsigned short* __restrict__ U,
      const unsigned short* __restrict__ Vt, const float* __restrict__ bias,
      float* __restrict__ out, int r0){
  __shared__ __align__(16) unsigned short As[128*32];
  __shared__ __align__(16) unsigned short Bs[128*32];
  const int tid  = threadIdx.x;
  const int lane = tid & 63;
  const int wr = ((tid >> 6) & 1) * 64;
  const int wc = (tid >> 7) * 64;

  floatx4 acc[4][4];
  #pragma unroll
  for (int a = 0; a < 4; ++a)
    #pragma unroll
    for (int c = 0; c < 4; ++c) acc[a][c] = (floatx4){0.f,0.f,0.f,0.f};

  const int srow = tid >> 2;            // 0..63 (+64 via rstep)
  const int scol = (tid & 3) << 4;      // byte offset in 64B row chunk
  const char* Ag = (const char*)U  + ((size_t)(blockIdx.x*128 + srow))*(QDIM*2) + scol;
  const char* Bg = (const char*)Vt + ((size_t)srow)*(QDIM*2) + scol;
  const size_t rstep = (size_t)64*QDIM*2;

  char* AsB = (char*)As;
  char* BsB = (char*)Bs;
  const int ar = lane & 15;
  const int ko = (lane >> 4) << 4;      // byte offset of 8-bf16 k-chunk

  for (int kt = 0; kt < KIT; ++kt){
    size_t qb = (size_t)kt * 64;
    gload16(Ag + qb,         AsB + tid*16);
    gload16(Ag + rstep + qb, AsB + 4096 + tid*16);
    gload16(Bg + qb,         BsB + tid*16);
    gload16(Bg + rstep + qb, BsB + 4096 + tid*16);
    __syncthreads();
    bf16x8 av[4], bv[4];
    #pragma unroll
    for (int f = 0; f < 4; ++f)
      av[f] = *(const bf16x8*)(AsB + (wr + f*16 + ar)*64 + ko);
    #pragma unroll
    for (int f = 0; f < 4; ++f)
      bv[f] = *(const bf16x8*)(BsB + (wc + f*16 + ar)*64 + ko);
    #pragma unroll
    for (int fr = 0; fr < 4; ++fr)
      #pragma unroll
      for (int fc = 0; fc < 4; ++fc)
        acc[fr][fc] = __builtin_amdgcn_mfma_f32_16x16x32_bf16(av[fr], bv[fc], acc[fr][fc], 0, 0, 0);
    __syncthreads();
  }

  const int rbase = r0 + blockIdx.x*128;
  const int b = rbase >> 14;
  float* ob = out + ((size_t)b << 21);
  #pragma unroll
  for (int fc = 0; fc < 4; ++fc){
    int i = wc + fc*16 + (lane & 15);
    float bi = bias[i];
    #pragma unroll
    for (int fr = 0; fr < 4; ++fr){
      int l = (rbase + wr + fr*16 + ((lane >> 4) << 2)) & (NS-1);
      float4 v;
      v.x = acc[fr][fc][0] + bi;
      v.y = acc[fr][fc][1] + bi;
      v.z = acc[fr][fc][2] + bi;
      v.w = acc[fr][fc][3] + bi;
      *(float4*)(ob + ((size_t)i << 14) + l) = v;
    }
  }
}

// ---------------- Naive zero-workspace fallback (correctness net) ----------------
__global__ __launch_bounds__(256) void k_naive(const float* __restrict__ x,
      const int* __restrict__ nb, const float* __restrict__ coords,
      const float* __restrict__ W1, const float* __restrict__ b1,
      const float* __restrict__ W2, const float* __restrict__ b2,
      const float* __restrict__ W3, const float* __restrict__ b3,
      const float* __restrict__ bias, float* __restrict__ out){
  __shared__ __align__(16) float hk[KNB][68];
  __shared__ int pk[KNB];
  __shared__ __align__(16) float xg[4][KNB][128];
  __shared__ __align__(16) float ul[128][66];
  int tid = threadIdx.x;
  int l = blockIdx.x;
  int lane = tid & 63, wid = tid >> 6;
  if (tid < KNB) pk[tid] = nb[tid*NS + l];
  for (int k = wid; k < KNB; k += 4){
    int pt = k*NS + l;
    float c0 = coords[2*pt], c1 = coords[2*pt+1];
    float z  = fmaf(c0, W1[lane], fmaf(c1, W1[64+lane], b1[lane]));
    float h1 = sinf(W0C*z);
    float a = b2[lane];
    for (int mp = 0; mp < 64; ++mp)
      a = fmaf(__shfl(h1, mp, 64), W2[mp*64+lane], a);
    hk[k][lane] = sinf(a);
    if (lane == 0){ hk[k][64] = 1.f; hk[k][65] = 0.f; }
  }
  __syncthreads();
  for (int idx = tid; idx < 4*KNB*128; idx += 256){
    int b = idx / (KNB*128);
    int r = idx - b*KNB*128;
    int k = r >> 7;
    int j = r & 127;
    xg[b][k][j] = x[((size_t)b*CIN + j)*NIN + pk[k]];
  }
  __syncthreads();
  for (int b = 0; b < 4; ++b){
    for (int idx = tid; idx < 128*65; idx += 256){
      int j = idx / 65, m = idx - j*65;
      float s = 0.f;
      for (int k = 0; k < KNB; ++k) s = fmaf(xg[b][k][j], hk[k][m], s);
      ul[j][m] = s;
    }
    __syncthreads();
    if (tid < 128){
      int i = tid;
      float v = bias[i];
      for (int j = 0; j < 128; ++j){
        const float* wcol = W3 + i*128 + j;
        for (int m = 0; m < 64; ++m)
          v = fmaf(ul[j][m], wcol[(size_t)m*16384], v);
        v = fmaf(ul[j][64], b3[i*128+j], v);
      }
      out[((size_t)b<<21) + ((size_t)i<<14) + l] = v;
    }
    __syncthreads();
  }
}

extern "C" void kernel_launch(void* const* d_in, const int* in_sizes, int n_in,
                              void* d_out, int out_size, void* d_ws, size_t ws_size,
                              hipStream_t stream) {
  const float* x      = (const float*)d_in[0];
  const int*   nb     = (const int*)  d_in[1];
  const float* coords = (const float*)d_in[2];
  const float* W1     = (const float*)d_in[3];
  const float* b1     = (const float*)d_in[4];
  const float* W2     = (const float*)d_in[5];
  const float* b2     = (const float*)d_in[6];
  const float* W3     = (const float*)d_in[7];
  const float* b3     = (const float*)d_in[8];
  const float* bias   = (const float*)d_in[9];
  float* out = (float*)d_out;

  const size_t VT_BYTES = (size_t)COUT*QDIM*2;          //  2,162,688
  const size_t H_BYTES  = (size_t)KNB*NS*MCH*4;         // 38,928,384
  const size_t XT_BYTES = (size_t)4*NIN*CIN*2;          // 16,777,216 (bf16)
  const size_t FIXED    = VT_BYTES + H_BYTES + XT_BYTES;// 57,868,288
  const size_t ROWB     = (size_t)QDIM*2;               // 16,896 B per U row
  const int    RTOT     = 4*NS;                         // 65,536 rows

  // choose chunk size (multiple of 128 rows) that fits the workspace
  int CH = 0;
  if (ws_size > FIXED + 128*ROWB) {
    size_t rows = (ws_size - FIXED) / ROWB;
    CH = (int)((rows / 128) * 128);
    if (CH > RTOT) CH = RTOT;
  }

  if (CH >= 128) {
    char* ws = (char*)d_ws;
    unsigned short* Vt = (unsigned short*)ws;
    float*          h  = (float*)(ws + VT_BYTES);
    unsigned short* xT = (unsigned short*)(ws + VT_BYTES + H_BYTES);
    unsigned short* U  = (unsigned short*)(ws + FIXED);

    k0_vt<<<(COUT*QDIM + 255)/256, 256, 0, stream>>>(W3, b3, Vt);
    k1_mlp<<<(KNB*NS)/4, 256, 0, stream>>>(coords, W1, b1, W2, b2, h);
    k_tr<<<dim3(NIN/32, CIN/32, 4), dim3(32, 8), 0, stream>>>(x, xT);

    for (int r0 = 0; r0 < RTOT; r0 += CH) {
      int rows = RTOT - r0; if (rows > CH) rows = CH;
      k2_uform<<<rows, 128, 0, stream>>>(xT, h, nb, U, r0);
      k3_gemm<<<rows/128, 256, 0, stream>>>(U, Vt, bias, out, r0);
    }
  } else {
    // zero-workspace correctness net (slow; not expected to run)
    k_naive<<<NS, 256, 0, stream>>>(x, nb, coords, W1, b1, W2, b2, W3, b3, bias, out);
  }
  (void)in_sizes; (void)n_in; (void)out_size;
}

// Round 3
// 1587.457 us; speedup vs baseline: 1.0948x; 1.0948x over previous
//
#include <hip/hip_runtime.h>

#define NS   16384
#define NIN  16384
#define CIN  128
#define COUT 128
#define KNB  9
#define MCH  66              // 64 MLP channels + 1 (b3 ones) + 1 zero pad
#define QDIM (CIN*MCH)       // 8448, q = m*128 + j (j-fastest)
#define SPL  8               // split-K factor
#define QSL  (QDIM/SPL)      // 1056
#define KITS (QSL/32)        // 33
#define W0C  30.0f

typedef __bf16 bf16;
typedef bf16  bf16x8  __attribute__((ext_vector_type(8)));
typedef float floatx4 __attribute__((ext_vector_type(4)));
typedef unsigned int u32;

__device__ inline unsigned short f2bf(float f){
  u32 u = __float_as_uint(f);
  u += 0x7fffu + ((u >> 16) & 1u);   // round-to-nearest-even
  return (unsigned short)(u >> 16);
}
__device__ inline float bf2f(unsigned short s){
  return __uint_as_float((u32)s << 16);
}

__device__ inline void gload16(const void* g, void* s){
  __builtin_amdgcn_global_load_lds(
      (const __attribute__((address_space(1))) u32*)g,
      (__attribute__((address_space(3))) u32*)s, 16, 0, 0);
}

// ---------------- K0: Vt[i][q] bf16, q = m*128+j ----------------
__global__ void k0_vt(const float* __restrict__ W3, const float* __restrict__ b3,
                      unsigned short* __restrict__ Vt){
  int idx = blockIdx.x*256 + threadIdx.x;
  if (idx >= COUT*QDIM) return;
  int i = idx / QDIM;
  int q = idx - i*QDIM;
  int m = q >> 7;
  int j = q & 127;
  float v = 0.f;
  if (m < 64)       v = W3[m*16384 + i*128 + j];
  else if (m == 64) v = b3[i*128 + j];
  Vt[idx] = f2bf(v);
}

// ---------------- K1: SIREN MLP (fp32 math, bf16 out) ----------------
__global__ __launch_bounds__(256) void k1_mlp(const float* __restrict__ coords,
      const float* __restrict__ W1, const float* __restrict__ b1,
      const float* __restrict__ W2, const float* __restrict__ b2,
      unsigned short* __restrict__ h){
  int lane = threadIdx.x & 63;
  int pt = blockIdx.x*4 + (threadIdx.x >> 6);
  float c0 = coords[2*pt], c1 = coords[2*pt+1];
  float z  = fmaf(c0, W1[lane], fmaf(c1, W1[64+lane], b1[lane]));
  float h1 = sinf(W0C * z);
  float acc = b2[lane];
  #pragma unroll
  for (int mp = 0; mp < 64; ++mp)
    acc = fmaf(__shfl(h1, mp, 64), W2[mp*64 + lane], acc);
  float h2 = sinf(acc);
  size_t base = (size_t)pt * MCH;
  h[base + lane] = f2bf(h2);
  if (lane == 0){ h[base+64] = 0x3F80; h[base+65] = 0; }  // 1.0, 0.0
}

// ---------------- K1b: transpose x[b][j][p] -> xT[b][p][j] (bf16) ----------------
__global__ void k_tr(const float* __restrict__ x, unsigned short* __restrict__ xT){
  __shared__ __align__(16) float t[32][33];
  int b  = blockIdx.z;
  int j0 = blockIdx.y*32;
  int p0 = blockIdx.x*32;
  int tx = threadIdx.x, ty = threadIdx.y;
  const float*    xb  = x  + (size_t)b*CIN*NIN;
  unsigned short* xTb = xT + (size_t)b*NIN*CIN;
  #pragma unroll
  for (int n = 0; n < 4; ++n)
    t[ty+8*n][tx] = xb[(size_t)(j0+ty+8*n)*NIN + p0+tx];
  __syncthreads();
  #pragma unroll
  for (int n = 0; n < 4; ++n)
    xTb[(size_t)(p0+ty+8*n)*CIN + j0+tx] = f2bf(t[tx][ty+8*n]);
}

// ---------------- K_init: out[b][i][l] = bias[i] ----------------
__global__ __launch_bounds__(256) void k_init(const float* __restrict__ bias,
                                              float* __restrict__ out){
  int idx = blockIdx.x*256 + threadIdx.x;       // one float4 per thread
  if (idx >= 4*COUT*(NS/4)) return;
  int i = (idx >> 12) & 127;
  float bv = bias[i];
  float4 v = {bv, bv, bv, bv};
  *((float4*)out + idx) = v;
}

// ---------------- K2: U[r][m*128+j] = sum_k xT[b][n[k,l]][j]*h[kl][m] ----------------
__global__ __launch_bounds__(128) void k2_uform(const unsigned short* __restrict__ xT,
      const unsigned short* __restrict__ h, const int* __restrict__ nb,
      unsigned short* __restrict__ U, int r0){
  __shared__ __align__(16) float hl[KNB][68];
  __shared__ int pk[KNB];
  int tid = threadIdx.x;
  int r = r0 + blockIdx.x;
  int b = r >> 14;
  int l = r & (NS-1);
  for (int idx = tid; idx < KNB*MCH; idx += 128){
    int k = idx / MCH;
    int m = idx - k*MCH;
    hl[k][m] = bf2f(h[(size_t)(k*NS + l)*MCH + m]);
  }
  if (tid < KNB) pk[tid] = nb[tid*NS + l];
  __syncthreads();
  const unsigned short* xb = xT + ((size_t)b << 21);   // b*NIN*CIN
  float acc[65];
  #pragma unroll
  for (int t = 0; t < 65; ++t) acc[t] = 0.f;
  #pragma unroll
  for (int k = 0; k < KNB; ++k){
    float xv = bf2f(xb[((size_t)pk[k] << 7) + tid]);
    #pragma unroll
    for (int t = 0; t < 16; ++t){
      float4 hv = *(const float4*)&hl[k][4*t];
      acc[4*t+0] = fmaf(xv, hv.x, acc[4*t+0]);
      acc[4*t+1] = fmaf(xv, hv.y, acc[4*t+1]);
      acc[4*t+2] = fmaf(xv, hv.z, acc[4*t+2]);
      acc[4*t+3] = fmaf(xv, hv.w, acc[4*t+3]);
    }
    acc[64] += xv;   // h channel 64 == 1  (b3 path)
  }
  // j-fastest store: wave writes 128B contiguous per m -> full-line coalescing
  unsigned short* dst = U + (size_t)blockIdx.x*QDIM + tid;
  #pragma unroll
  for (int m = 0; m < 65; ++m) dst[m << 7] = f2bf(acc[m]);
  dst[65 << 7] = 0;                              // zero pad channel
}

// ---------------- K3: split-K MFMA GEMM, atomic f32 accumulate ----------------
__global__ __launch_bounds__(256) void k3_gemm(const unsigned short* __restrict__ U,
      const unsigned short* __restrict__ Vt,
      float* __restrict__ out, int r0){
  __shared__ __align__(16) unsigned short As[128*32];
  __shared__ __align__(16) unsigned short Bs[128*32];
  const int tid  = threadIdx.x;
  const int lane = tid & 63;
  const int wr = ((tid >> 6) & 1) * 64;
  const int wc = (tid >> 7) * 64;
  const int s  = blockIdx.y;                  // split index

  floatx4 acc[4][4];
  #pragma unroll
  for (int a = 0; a < 4; ++a)
    #pragma unroll
    for (int c = 0; c < 4; ++c) acc[a][c] = (floatx4){0.f,0.f,0.f,0.f};

  const int srow = tid >> 2;
  const int scol = (tid & 3) << 4;
  const char* Ag = (const char*)U  + ((size_t)(blockIdx.x*128 + srow))*(QDIM*2) + scol;
  const char* Bg = (const char*)Vt + ((size_t)srow)*(QDIM*2) + scol;
  const size_t rstep = (size_t)64*QDIM*2;

  char* AsB = (char*)As;
  char* BsB = (char*)Bs;
  const int ar = lane & 15;
  const int ko = (lane >> 4) << 4;

  for (int kt = 0; kt < KITS; ++kt){
    size_t qb = (size_t)(s*KITS + kt) * 64;
    gload16(Ag + qb,         AsB + tid*16);
    gload16(Ag + rstep + qb, AsB + 4096 + tid*16);
    gload16(Bg + qb,         BsB + tid*16);
    gload16(Bg + rstep + qb, BsB + 4096 + tid*16);
    __syncthreads();
    bf16x8 av[4], bv[4];
    #pragma unroll
    for (int f = 0; f < 4; ++f)
      av[f] = *(const bf16x8*)(AsB + (wr + f*16 + ar)*64 + ko);
    #pragma unroll
    for (int f = 0; f < 4; ++f)
      bv[f] = *(const bf16x8*)(BsB + (wc + f*16 + ar)*64 + ko);
    #pragma unroll
    for (int fr = 0; fr < 4; ++fr)
      #pragma unroll
      for (int fc = 0; fc < 4; ++fc)
        acc[fr][fc] = __builtin_amdgcn_mfma_f32_16x16x32_bf16(av[fr], bv[fc], acc[fr][fc], 0, 0, 0);
    __syncthreads();
  }

  const int rbase = r0 + blockIdx.x*128;
  const int b = rbase >> 14;
  float* ob = out + ((size_t)b << 21);
  #pragma unroll
  for (int fc = 0; fc < 4; ++fc){
    int i = wc + fc*16 + (lane & 15);
    #pragma unroll
    for (int fr = 0; fr < 4; ++fr){
      int l = (rbase + wr + fr*16 + ((lane >> 4) << 2)) & (NS-1);
      float* p = ob + ((size_t)i << 14) + l;
      unsafeAtomicAdd(p+0, acc[fr][fc][0]);
      unsafeAtomicAdd(p+1, acc[fr][fc][1]);
      unsafeAtomicAdd(p+2, acc[fr][fc][2]);
      unsafeAtomicAdd(p+3, acc[fr][fc][3]);
    }
  }
}

// ---------------- Naive zero-workspace fallback (correctness net) ----------------
__global__ __launch_bounds__(256) void k_naive(const float* __restrict__ x,
      const int* __restrict__ nb, const float* __restrict__ coords,
      const float* __restrict__ W1, const float* __restrict__ b1,
      const float* __restrict__ W2, const float* __restrict__ b2,
      const float* __restrict__ W3, const float* __restrict__ b3,
      const float* __restrict__ bias, float* __restrict__ out){
  __shared__ __align__(16) float hk[KNB][68];
  __shared__ int pk[KNB];
  __shared__ __align__(16) float xg[4][KNB][128];
  __shared__ __align__(16) float ul[128][66];
  int tid = threadIdx.x;
  int l = blockIdx.x;
  int lane = tid & 63, wid = tid >> 6;
  if (tid < KNB) pk[tid] = nb[tid*NS + l];
  for (int k = wid; k < KNB; k += 4){
    int pt = k*NS + l;
    float c0 = coords[2*pt], c1 = coords[2*pt+1];
    float z  = fmaf(c0, W1[lane], fmaf(c1, W1[64+lane], b1[lane]));
    float h1 = sinf(W0C*z);
    float a = b2[lane];
    for (int mp = 0; mp < 64; ++mp)
      a = fmaf(__shfl(h1, mp, 64), W2[mp*64+lane], a);
    hk[k][lane] = sinf(a);
    if (lane == 0){ hk[k][64] = 1.f; hk[k][65] = 0.f; }
  }
  __syncthreads();
  for (int idx = tid; idx < 4*KNB*128; idx += 256){
    int b = idx / (KNB*128);
    int r = idx - b*KNB*128;
    int k = r >> 7;
    int j = r & 127;
    xg[b][k][j] = x[((size_t)b*CIN + j)*NIN + pk[k]];
  }
  __syncthreads();
  for (int b = 0; b < 4; ++b){
    for (int idx = tid; idx < 128*65; idx += 256){
      int j = idx / 65, m = idx - j*65;
      float s = 0.f;
      for (int k = 0; k < KNB; ++k) s = fmaf(xg[b][k][j], hk[k][m], s);
      ul[j][m] = s;
    }
    __syncthreads();
    if (tid < 128){
      int i = tid;
      float v = bias[i];
      for (int j = 0; j < 128; ++j){
        const float* wcol = W3 + i*128 + j;
        for (int m = 0; m < 64; ++m)
          v = fmaf(ul[j][m], wcol[(size_t)m*16384], v);
        v = fmaf(ul[j][64], b3[i*128+j], v);
      }
      out[((size_t)b<<21) + ((size_t)i<<14) + l] = v;
    }
    __syncthreads();
  }
}

extern "C" void kernel_launch(void* const* d_in, const int* in_sizes, int n_in,
                              void* d_out, int out_size, void* d_ws, size_t ws_size,
                              hipStream_t stream) {
  const float* x      = (const float*)d_in[0];
  const int*   nb     = (const int*)  d_in[1];
  const float* coords = (const float*)d_in[2];
  const float* W1     = (const float*)d_in[3];
  const float* b1     = (const float*)d_in[4];
  const float* W2     = (const float*)d_in[5];
  const float* b2     = (const float*)d_in[6];
  const float* W3     = (const float*)d_in[7];
  const float* b3     = (const float*)d_in[8];
  const float* bias   = (const float*)d_in[9];
  float* out = (float*)d_out;

  const size_t VT_BYTES = (size_t)COUT*QDIM*2;          //  2,162,688
  const size_t H_BYTES  = (size_t)KNB*NS*MCH*2;         // 19,464,192 (bf16)
  const size_t XT_BYTES = (size_t)4*NIN*CIN*2;          // 16,777,216 (bf16)
  const size_t FIXED    = VT_BYTES + H_BYTES + XT_BYTES;// 38,404,096
  const size_t ROWB     = (size_t)QDIM*2;               // 16,896 B per U row
  const int    RTOT     = 4*NS;                         // 65,536 rows

  int CH = 0;
  if (ws_size > FIXED + 128*ROWB) {
    size_t rows = (ws_size - FIXED) / ROWB;
    CH = (int)((rows / 128) * 128);
    if (CH > RTOT) CH = RTOT;
  }

  if (CH >= 128) {
    char* ws = (char*)d_ws;
    unsigned short* Vt = (unsigned short*)ws;
    unsigned short* h  = (unsigned short*)(ws + VT_BYTES);
    unsigned short* xT = (unsigned short*)(ws + VT_BYTES + H_BYTES);
    unsigned short* U  = (unsigned short*)(ws + FIXED);

    k0_vt<<<(COUT*QDIM + 255)/256, 256, 0, stream>>>(W3, b3, Vt);
    k1_mlp<<<(KNB*NS)/4, 256, 0, stream>>>(coords, W1, b1, W2, b2, h);
    k_tr<<<dim3(NIN/32, CIN/32, 4), dim3(32, 8), 0, stream>>>(x, xT);
    k_init<<<(4*COUT*(NS/4) + 255)/256, 256, 0, stream>>>(bias, out);

    for (int r0 = 0; r0 < RTOT; r0 += CH) {
      int rows = RTOT - r0; if (rows > CH) rows = CH;
      k2_uform<<<rows, 128, 0, stream>>>(xT, h, nb, U, r0);
      k3_gemm<<<dim3(rows/128, SPL), 256, 0, stream>>>(U, Vt, out, r0);
    }
  } else {
    k_naive<<<NS, 256, 0, stream>>>(x, nb, coords, W1, b1, W2, b2, W3, b3, bias, out);
  }
  (void)in_sizes; (void)n_in; (void)out_size;
}